// Round 4
// baseline (22536.028 us; speedup 1.0000x reference)
//
#include <hip/hip_runtime.h>
#include <math.h>

#define T_SEQ 120
#define BATCH 256
#define HID   512
#define G3    1536            // 3*HID
#define MROWS (BATCH*T_SEQ)   // 30720
#define TS    (T_SEQ*HID)     // 61440, row stride per batch in out buffers
#define KGATE 122880          // T_SEQ*2*HID

typedef __attribute__((ext_vector_type(8))) short bf16x8;
typedef __attribute__((ext_vector_type(4))) float f32x4;

__device__ __forceinline__ unsigned short f2bf(float f) {
    union { float f; unsigned u; } x; x.f = f;
    unsigned r = x.u + 0x7fffu + ((x.u >> 16) & 1u);   // RNE
    return (unsigned short)(r >> 16);
}
__device__ __forceinline__ float sigm_fast(float x) {
    return 1.f / (1.f + __expf(-x));
}
__device__ __forceinline__ float tanh_fast(float x) {
    float e = __expf(2.f * x);
    return 1.f - 2.f / (e + 1.f);
}

// ---------------------------------------------------------------------------
// build x_in[m=b*120+t][d] = concat(X_lag, X_cov)[t,b,d]
// ---------------------------------------------------------------------------
__global__ void build_x(const float* __restrict__ X_lag,
                        const float* __restrict__ X_cov,
                        float* __restrict__ x_in)
{
    int idx = blockIdx.x * 256 + threadIdx.x;      // < 30720*64
    int d = idx & 63;
    int m = idx >> 6;                               // b*120 + t
    int b = m / 120, t = m - b * 120;
    float v;
    if (d < 32) v = X_lag[((size_t)t * BATCH + b) * 32 + d];
    else        v = X_cov[((size_t)t * BATCH + b) * 32 + (d - 32)];
    x_in[idx] = v;
}

__global__ void cast_whh0(const float* __restrict__ W, unsigned short* __restrict__ o)
{
    int i = blockIdx.x * 256 + threadIdx.x;        // < 786432
    o[i] = f2bf(W[i]);
}

// Wcat1 [1536][1024]: cols 0..511 = W_hh1, cols 512..1023 = W_ih1
__global__ void cast_wcat1(const float* __restrict__ Whh, const float* __restrict__ Wih,
                           unsigned short* __restrict__ o)
{
    int i = blockIdx.x * 256 + threadIdx.x;        // < 1572864
    int row = i >> 10, c = i & 1023;
    float v = (c < 512) ? Whh[row * 512 + c] : Wih[row * 512 + (c - 512)];
    o[i] = f2bf(v);
}

__global__ void mkbias(const float* __restrict__ bih0, const float* __restrict__ bhh0,
                       const float* __restrict__ bih1, const float* __restrict__ bhh1,
                       float* __restrict__ bcomb0, float* __restrict__ bc1)
{
    int n = blockIdx.x * 256 + threadIdx.x;        // < 1536
    bcomb0[n] = bih0[n] + (n < 1024 ? bhh0[n] : 0.f);
    bc1[n]    = bih1[n] + (n < 1024 ? bhh1[n] : 0.f);
}

// ---------------------------------------------------------------------------
// Tiled f32 GEMM with TRANSPOSED write for gx0:
// C[(t*256+b)*1536 + n] = bias[n] + sum_k A[m=b*120+t][k]*B[n][k]
// ---------------------------------------------------------------------------
__global__ __launch_bounds__(256) void gemm_abt_t(
    const float* __restrict__ A, const float* __restrict__ B,
    const float* __restrict__ bias, float* __restrict__ C,
    int M, int N, int K)
{
    __shared__ float As[32][129];
    __shared__ float Bs[32][129];
    int m0 = blockIdx.x * 128;
    int n0 = blockIdx.y * 128;
    int tid = threadIdx.x;
    int tx = tid & 15, ty = tid >> 4;
    float acc[8][8] = {};
    for (int k0 = 0; k0 < K; k0 += 32) {
        #pragma unroll
        for (int i = 0; i < 16; i++) {
            int e = tid + i * 256;
            int row = e >> 5, col = e & 31;
            As[col][row] = A[(size_t)(m0 + row) * K + k0 + col];
            Bs[col][row] = B[(size_t)(n0 + row) * K + k0 + col];
        }
        __syncthreads();
        #pragma unroll
        for (int kk = 0; kk < 32; kk++) {
            float a[8], b[8];
            #pragma unroll
            for (int i = 0; i < 8; i++) a[i] = As[kk][ty + i * 16];
            #pragma unroll
            for (int j = 0; j < 8; j++) b[j] = Bs[kk][tx + j * 16];
            #pragma unroll
            for (int i = 0; i < 8; i++)
                #pragma unroll
                for (int j = 0; j < 8; j++) acc[i][j] += a[i] * b[j];
        }
        __syncthreads();
    }
    #pragma unroll
    for (int i = 0; i < 8; i++) {
        int m = m0 + ty + i * 16;
        int b = m / 120, t = m - b * 120;
        #pragma unroll
        for (int j = 0; j < 8; j++) {
            int n = n0 + tx + j * 16;
            C[((size_t)t * 256 + b) * G3 + n] = acc[i][j] + bias[n];
        }
    }
}

// ---------------------------------------------------------------------------
// In-block dual-layer GRU recurrence. 16 blocks x 512 threads (8 waves).
// Block owns batches [bb0, bb0+16); wave wv owns h-cols [wv*64, wv*64+64).
// h state: bf16 in LDS (padded stride 520), f32 carry in registers.
// Per step: layer0 MFMA -> epilogue -> sync -> write h0s -> sync ->
//           layer1 MFMA (K-concat [h1|h0]) -> epilogue -> sync -> write -> sync.
// No inter-block communication anywhere.
// ---------------------------------------------------------------------------
__global__ __launch_bounds__(512) void gru_block(
    const float* __restrict__ gx0t,                  // [120][256][1536]
    const unsigned short* __restrict__ Whh0,         // [1536][512] bf16
    const unsigned short* __restrict__ Wcat1,        // [1536][1024] bf16
    const float* __restrict__ bhh0,
    const float* __restrict__ bhh1,
    const float* __restrict__ bc1,
    float* __restrict__ out0, float* __restrict__ out1)
{
    __shared__ unsigned short h0s[16][520];
    __shared__ unsigned short h1s[16][520];
    const int tid = threadIdx.x;
    const int wv  = tid >> 6, lane = tid & 63;
    const int l15 = lane & 15, l4 = lane >> 4;
    const int bb0 = blockIdx.x * 16;
    const int jb  = wv * 64;

    for (int i = tid; i < 16 * 520; i += 512) {
        ((unsigned short*)h0s)[i] = 0;
        ((unsigned short*)h1s)[i] = 0;
    }

    float bn0[4], br1[4], bz1[4], bnx1[4], bn1[4];
    #pragma unroll
    for (int jt = 0; jt < 4; jt++) {
        int j = jb + jt * 16 + l15;
        bn0[jt]  = bhh0[1024 + j];
        br1[jt]  = bc1[j];
        bz1[jt]  = bc1[512 + j];
        bnx1[jt] = bc1[1024 + j];
        bn1[jt]  = bhh1[1024 + j];
    }
    float hr0[4][4] = {}, hr1[4][4] = {};
    float hn[4][4];
    __syncthreads();

    for (int t = 0; t < T_SEQ; t++) {
        // ============================ layer 0 ============================
        {
            f32x4 ar[4], az[4], anh[4];
            #pragma unroll
            for (int jt = 0; jt < 4; jt++) {
                ar[jt] = (f32x4){0.f,0.f,0.f,0.f};
                az[jt] = (f32x4){0.f,0.f,0.f,0.f};
                anh[jt] = (f32x4){0.f,0.f,0.f,0.f};
            }
            #pragma unroll
            for (int ks = 0; ks < 16; ks++) {
                bf16x8 A = *(const bf16x8*)&h0s[l15][ks * 32 + 8 * l4];
                #pragma unroll
                for (int jt = 0; jt < 4; jt++) {
                    const unsigned short* wb =
                        Whh0 + (size_t)(jb + jt * 16 + l15) * 512 + ks * 32 + 8 * l4;
                    bf16x8 B0 = *(const bf16x8*)(wb);
                    bf16x8 B1 = *(const bf16x8*)(wb + 512 * 512);
                    bf16x8 B2 = *(const bf16x8*)(wb + 1024 * 512);
                    ar[jt]  = __builtin_amdgcn_mfma_f32_16x16x32_bf16(A, B0, ar[jt], 0, 0, 0);
                    az[jt]  = __builtin_amdgcn_mfma_f32_16x16x32_bf16(A, B1, az[jt], 0, 0, 0);
                    anh[jt] = __builtin_amdgcn_mfma_f32_16x16x32_bf16(A, B2, anh[jt], 0, 0, 0);
                }
            }
            #pragma unroll
            for (int jt = 0; jt < 4; jt++) {
                int j = jb + jt * 16 + l15;
                #pragma unroll
                for (int rr = 0; rr < 4; rr++) {
                    int b = bb0 + 4 * l4 + rr;
                    const float* gp = gx0t + ((size_t)t * 256 + b) * G3 + j;
                    float r = sigm_fast(gp[0] + ar[jt][rr]);
                    float z = sigm_fast(gp[512] + az[jt][rr]);
                    float n = tanh_fast(gp[1024] + r * (anh[jt][rr] + bn0[jt]));
                    float h = (1.f - z) * n + z * hr0[jt][rr];
                    hr0[jt][rr] = h;
                    out0[(size_t)b * TS + (size_t)t * 512 + j] = h;
                    hn[jt][rr] = h;
                }
            }
        }
        __syncthreads();                      // all waves done reading h0s(t-1)
        #pragma unroll
        for (int jt = 0; jt < 4; jt++)
            #pragma unroll
            for (int rr = 0; rr < 4; rr++)
                h0s[4 * l4 + rr][jb + jt * 16 + l15] = f2bf(hn[jt][rr]);
        __syncthreads();                      // h0s = h0_t visible

        // ============================ layer 1 ============================
        {
            f32x4 cr[4], cz[4], cnh[4], cnx[4];
            #pragma unroll
            for (int jt = 0; jt < 4; jt++) {
                cr[jt] = (f32x4){0.f,0.f,0.f,0.f};
                cz[jt] = (f32x4){0.f,0.f,0.f,0.f};
                cnh[jt] = (f32x4){0.f,0.f,0.f,0.f};
                cnx[jt] = (f32x4){0.f,0.f,0.f,0.f};
            }
            #pragma unroll
            for (int ks = 0; ks < 16; ks++) {              // h-part (k<512)
                bf16x8 A = *(const bf16x8*)&h1s[l15][ks * 32 + 8 * l4];
                #pragma unroll
                for (int jt = 0; jt < 4; jt++) {
                    const unsigned short* wb =
                        Wcat1 + (size_t)(jb + jt * 16 + l15) * 1024 + ks * 32 + 8 * l4;
                    bf16x8 B0 = *(const bf16x8*)(wb);
                    bf16x8 B1 = *(const bf16x8*)(wb + 512 * 1024);
                    bf16x8 B2 = *(const bf16x8*)(wb + 1024 * 1024);
                    cr[jt]  = __builtin_amdgcn_mfma_f32_16x16x32_bf16(A, B0, cr[jt], 0, 0, 0);
                    cz[jt]  = __builtin_amdgcn_mfma_f32_16x16x32_bf16(A, B1, cz[jt], 0, 0, 0);
                    cnh[jt] = __builtin_amdgcn_mfma_f32_16x16x32_bf16(A, B2, cnh[jt], 0, 0, 0);
                }
            }
            #pragma unroll
            for (int ks = 0; ks < 16; ks++) {              // x-part (k>=512), x = h0_t
                bf16x8 A = *(const bf16x8*)&h0s[l15][ks * 32 + 8 * l4];
                #pragma unroll
                for (int jt = 0; jt < 4; jt++) {
                    const unsigned short* wb =
                        Wcat1 + (size_t)(jb + jt * 16 + l15) * 1024 + 512 + ks * 32 + 8 * l4;
                    bf16x8 B0 = *(const bf16x8*)(wb);
                    bf16x8 B1 = *(const bf16x8*)(wb + 512 * 1024);
                    bf16x8 B2 = *(const bf16x8*)(wb + 1024 * 1024);
                    cr[jt]  = __builtin_amdgcn_mfma_f32_16x16x32_bf16(A, B0, cr[jt], 0, 0, 0);
                    cz[jt]  = __builtin_amdgcn_mfma_f32_16x16x32_bf16(A, B1, cz[jt], 0, 0, 0);
                    cnx[jt] = __builtin_amdgcn_mfma_f32_16x16x32_bf16(A, B2, cnx[jt], 0, 0, 0);
                }
            }
            #pragma unroll
            for (int jt = 0; jt < 4; jt++) {
                int j = jb + jt * 16 + l15;
                #pragma unroll
                for (int rr = 0; rr < 4; rr++) {
                    int b = bb0 + 4 * l4 + rr;
                    float r = sigm_fast(cr[jt][rr] + br1[jt]);
                    float z = sigm_fast(cz[jt][rr] + bz1[jt]);
                    float n = tanh_fast(cnx[jt][rr] + bnx1[jt] + r * (cnh[jt][rr] + bn1[jt]));
                    float h = (1.f - z) * n + z * hr1[jt][rr];
                    hr1[jt][rr] = h;
                    out1[(size_t)b * TS + (size_t)t * 512 + j] = h;
                    hn[jt][rr] = h;
                }
            }
        }
        __syncthreads();                      // all waves done reading h1s(t-1)
        #pragma unroll
        for (int jt = 0; jt < 4; jt++)
            #pragma unroll
            for (int rr = 0; rr < 4; rr++)
                h1s[4 * l4 + rr][jb + jt * 16 + l15] = f2bf(hn[jt][rr]);
        __syncthreads();                      // h1s = h1_t visible
    }
}

// ---------------------------------------------------------------------------
// z partials: 960 blocks = (t, half, c-quarter of 128).
// ---------------------------------------------------------------------------
__global__ __launch_bounds__(256) void zpart_kernel(
    const float* __restrict__ out, const float* __restrict__ Gw,
    float* __restrict__ zp)
{
    __shared__ float Os[128][33];
    __shared__ float Gs[128][33];
    int bk = blockIdx.x;
    int t = bk >> 3, half = (bk >> 2) & 1, cq = bk & 3;
    int tid = threadIdx.x;
    int tx = tid & 15, ty = tid >> 4;
    float acc[8][8] = {};
    int cbase = cq * 128;
    for (int c0 = cbase; c0 < cbase + 128; c0 += 32) {
        #pragma unroll
        for (int i = 0; i < 16; i++) {
            int e = tid + i * 256;
            int row = e >> 5, col = e & 31;
            Os[row][col] = out[(size_t)(row + half * 128) * TS + (size_t)t * 512 + c0 + col];
            float v = 0.f;
            if (row < 120)
                v = Gw[(size_t)row * KGATE + (size_t)t * 1024 + half * 512 + c0 + col];
            Gs[row][col] = v;
        }
        __syncthreads();
        #pragma unroll
        for (int kk = 0; kk < 32; kk++) {
            float a[8], g[8];
            #pragma unroll
            for (int i = 0; i < 8; i++) a[i] = Os[ty + i * 16][kk];
            #pragma unroll
            for (int j = 0; j < 8; j++) g[j] = Gs[tx + j * 16][kk];
            #pragma unroll
            for (int i = 0; i < 8; i++)
                #pragma unroll
                for (int j = 0; j < 8; j++) acc[i][j] += a[i] * g[j];
        }
        __syncthreads();
    }
    float* zb = zp + (size_t)bk * (128 * 120);
    #pragma unroll
    for (int i = 0; i < 8; i++) {
        int ii = ty + i * 16;
        #pragma unroll
        for (int j = 0; j < 8; j++) {
            int r = tx + j * 16;
            if (r < 120) zb[ii * 120 + r] = acc[i][j];
        }
    }
}

__global__ void zreduce(const float* __restrict__ zp,
                        const float* __restrict__ gate_b_l,
                        float* __restrict__ z)
{
    int idx = blockIdx.x * 256 + threadIdx.x;
    if (idx >= 128 * 120) return;
    float s = 0.f;
    for (int c = 0; c < 960; c++) s += zp[(size_t)c * (128 * 120) + idx];
    z[idx] = s + gate_b_l[idx % 120];
}

__global__ __launch_bounds__(128) void bn_col(
    const float* __restrict__ z, const float* __restrict__ gamma,
    const float* __restrict__ beta, float* __restrict__ wm)
{
    int r = blockIdx.x, i = threadIdx.x;
    __shared__ float sh[2];
    float v = z[i * 120 + r];
    float s = v;
    for (int o = 32; o > 0; o >>= 1) s += __shfl_down(s, o);
    if ((i & 63) == 0) sh[i >> 6] = s;
    __syncthreads();
    float m = (sh[0] + sh[1]) * (1.f / 128.f);
    __syncthreads();
    float d = (v - m) * (v - m);
    for (int o = 32; o > 0; o >>= 1) d += __shfl_down(d, o);
    if ((i & 63) == 0) sh[i >> 6] = d;
    __syncthreads();
    float var = (sh[0] + sh[1]) * (1.f / 128.f);
    float w = 1.f / (1.f + expf(-(gamma[r] * (v - m) / sqrtf(var + 1e-5f) + beta[r])));
    __syncthreads();
    float ws_ = w;
    for (int o = 32; o > 0; o >>= 1) ws_ += __shfl_down(ws_, o);
    if ((i & 63) == 0) sh[i >> 6] = ws_;
    __syncthreads();
    if (i == 0) wm[r] = (sh[0] + sh[1]) * (1.f / 128.f);
}

__global__ __launch_bounds__(128) void softmax120(
    const float* __restrict__ wm, float* __restrict__ g_out,
    float* __restrict__ g_ws)
{
    int i = threadIdx.x;
    __shared__ float sh[2];
    float v = (i < 120) ? wm[i] : -1e30f;
    float m = v;
    for (int o = 32; o > 0; o >>= 1) m = fmaxf(m, __shfl_down(m, o));
    if ((i & 63) == 0) sh[i >> 6] = m;
    __syncthreads();
    float mx = fmaxf(sh[0], sh[1]);
    float e = (i < 120) ? expf(v - mx) : 0.f;
    __syncthreads();
    float se = e;
    for (int o = 32; o > 0; o >>= 1) se += __shfl_down(se, o);
    if ((i & 63) == 0) sh[i >> 6] = se;
    __syncthreads();
    float sum = sh[0] + sh[1];
    if (i < 120) { float g = e / sum; g_out[i] = g; g_ws[i] = g; }
}

__global__ void halfmeans(const float* __restrict__ out,
                          float* __restrict__ ms, float* __restrict__ mt)
{
    int idx = blockIdx.x * 256 + threadIdx.x;
    int half = idx >= TS;
    int tc = idx - half * TS;
    const float* base = out + (size_t)(half * 128) * TS + tc;
    float s = 0.f;
    for (int i = 0; i < 128; i++) s += base[(size_t)i * TS];
    s *= (1.f / 128.f);
    if (half) mt[tc] = s; else ms[tc] = s;
}

// coalesced: thread c accumulates over windowed j, block-reduce 512 lanes
__global__ __launch_bounds__(512) void transfer_part(
    const float* __restrict__ ms, const float* __restrict__ mt,
    const float* __restrict__ gw, const int* __restrict__ lenw,
    float* __restrict__ part)
{
    int t = blockIdx.x, c = threadIdx.x;
    int lw = lenw[0];
    int j0 = t - lw; if (j0 < 0) j0 = 0;
    int j1 = t + lw; if (j1 > 119) j1 = 119;
    float m_c = ms[(size_t)t * 512 + c];
    float acc = 0.f;
    for (int j = j0; j <= j1; j++) {
        float d = m_c - mt[(size_t)j * 512 + c];
        acc += d * d;
    }
    for (int o = 32; o > 0; o >>= 1) acc += __shfl_down(acc, o);
    __shared__ float sh[8];
    if ((c & 63) == 0) sh[c >> 6] = acc;
    __syncthreads();
    if (c == 0) {
        float s = 0.f;
        #pragma unroll
        for (int k = 0; k < 8; k++) s += sh[k];
        part[t] = gw[t] * s;
    }
}

// wave-per-row prediction head: grid = dsl*64 blocks, 4 waves each
__global__ __launch_bounds__(256) void yhat_kernel(
    const float* __restrict__ out1, const float* __restrict__ y,
    const float* __restrict__ fcW, const float* __restrict__ fcb,
    int dsl, float* __restrict__ dout, float* __restrict__ lp_rows)
{
    int wid = blockIdx.x * 4 + (threadIdx.x >> 6);   // 0..dsl*256-1
    int lane = threadIdx.x & 63;
    int tt = wid >> 8, b = wid & 255;
    int t = T_SEQ - dsl + tt;
    const float* row = out1 + (size_t)b * TS + (size_t)t * 512;
    float s = 0.f;
    #pragma unroll
    for (int k = 0; k < 8; k++) s += row[lane + 64 * k] * fcW[lane + 64 * k];
    for (int o = 32; o > 0; o >>= 1) s += __shfl_down(s, o);
    if (lane == 0) {
        float loc = s + fcb[0];
        float sp = fmaxf(loc, 0.f) + log1pf(expf(-fabsf(loc)));
        float scale = sp + 1e-6f;
        dout[2 + tt * 256 + b] = loc;
        dout[2 + dsl * 256 + tt * 256 + b] = scale;
        float yt = y[(size_t)t * 256 + b];
        float u = (yt - loc) / scale;
        lp_rows[wid] = -0.5f * u * u - logf(scale) - 0.91893853320467274f;
    }
}

__global__ __launch_bounds__(64) void finalize(
    const float* __restrict__ lp_rows, const float* __restrict__ part0,
    const float* __restrict__ part1, float* __restrict__ dout, int n_lp)
{
    int i = threadIdx.x;
    float s = 0.f;
    for (int k = i; k < n_lp; k += 64) s += lp_rows[k];
    for (int o = 32; o > 0; o >>= 1) s += __shfl_down(s, o);
    float tr = 0.f;
    for (int k = i; k < 120; k += 64) tr += part0[k] + part1[k];
    for (int o = 32; o > 0; o >>= 1) tr += __shfl_down(tr, o);
    if (i == 0) {
        float ly = -s / (float)n_lp;
        dout[1] = ly;
        dout[0] = ly + tr;
    }
}

// ---------------------------------------------------------------------------
extern "C" void kernel_launch(void* const* d_in, const int* in_sizes, int n_in,
                              void* d_out, int out_size, void* d_ws, size_t ws_size,
                              hipStream_t stream)
{
    const float* X_cov  = (const float*)d_in[1];
    const float* X_lag  = (const float*)d_in[2];
    const float* y      = (const float*)d_in[3];
    const int*   lenw   = (const int*)d_in[5];
    const float* W_ih0  = (const float*)d_in[6];
    const float* W_hh0  = (const float*)d_in[7];
    const float* b_ih0  = (const float*)d_in[8];
    const float* b_hh0  = (const float*)d_in[9];
    const float* W_ih1  = (const float*)d_in[10];
    const float* W_hh1  = (const float*)d_in[11];
    const float* b_ih1  = (const float*)d_in[12];
    const float* b_hh1  = (const float*)d_in[13];
    const float* gate_W = (const float*)d_in[14];
    const float* gate_b = (const float*)d_in[15];
    const float* bn_g   = (const float*)d_in[16];
    const float* bn_b   = (const float*)d_in[17];
    const float* fc_W   = (const float*)d_in[18];
    const float* fc_b   = (const float*)d_in[19];
    float* dout = (float*)d_out;
    float* ws   = (float*)d_ws;

    // workspace layout (float offsets). Aliases are time-disjoint:
    //  - zp aliases gx0t (gx0t dead after gru_block)
    //  - lp_rows aliases x_in (dead after gemm_abt_t)
    float* x_in    = ws;                         // 1,966,080
    float* gx0t    = ws + 1966080;               // 47,185,920  [120][256][1536]
    float* out0    = ws + 49152000;              // 15,728,640
    float* out1    = ws + 64880640;              // 15,728,640
    unsigned short* Whh0bf  = (unsigned short*)(ws + 80609280);  // 786,432 ush
    unsigned short* Wcat1bf = (unsigned short*)(ws + 81002496);  // 1,572,864 ush
    float* zmat    = ws + 84295680;              // 15,360
    float* wm      = ws + 84311040;              // 120
    float* gw_ws   = ws + 84311160;              // 240
    float* msb     = ws + 84311400;              // 61,440
    float* mtb     = ws + 84372840;              // 61,440
    float* part    = ws + 84434280;              // 240
    float* bcomb0  = ws + 84434560;              // 1536
    float* bc1     = ws + 84436096;              // 1536
    float* zp      = gx0t;                       // 14,745,600 (alias)
    float* lp_rows = x_in;                       // dsl*256 (alias)

    int dsl = (out_size - 2 - 2 * T_SEQ) / (2 * BATCH);   // = 24

    build_x<<<dim3(7680), 256, 0, stream>>>(X_lag, X_cov, x_in);
    cast_whh0<<<dim3(3072), 256, 0, stream>>>(W_hh0, Whh0bf);
    cast_wcat1<<<dim3(6144), 256, 0, stream>>>(W_hh1, W_ih1, Wcat1bf);
    mkbias<<<dim3(6), 256, 0, stream>>>(b_ih0, b_hh0, b_ih1, b_hh1, bcomb0, bc1);

    gemm_abt_t<<<dim3(240, 12), 256, 0, stream>>>(x_in, W_ih0, bcomb0, gx0t,
                                                  MROWS, G3, 64);

    gru_block<<<dim3(16), 512, 0, stream>>>(gx0t, Whh0bf, Wcat1bf,
                                            b_hh0, b_hh1, bc1, out0, out1);

    for (int l = 0; l < 2; l++) {
        const float* o = l ? out1 : out0;
        zpart_kernel<<<960, 256, 0, stream>>>(o, gate_W + (size_t)l * 120 * KGATE, zp);
        zreduce<<<60, 256, 0, stream>>>(zp, gate_b + l * 120, zmat);
        bn_col<<<120, 128, 0, stream>>>(zmat, bn_g + l * 120, bn_b + l * 120, wm);
        softmax120<<<1, 128, 0, stream>>>(wm, dout + 2 + 2 * dsl * 256 + l * 120,
                                          gw_ws + l * 120);
        halfmeans<<<480, 256, 0, stream>>>(o, msb, mtb);
        transfer_part<<<120, 512, 0, stream>>>(msb, mtb, gw_ws + l * 120, lenw,
                                               part + l * 120);
    }

    yhat_kernel<<<dsl * 64, 256, 0, stream>>>(out1, y, fc_W, fc_b, dsl, dout, lp_rows);
    finalize<<<1, 64, 0, stream>>>(lp_rows, part, part + 120, dout, dsl * 256);
}

// Round 5
// 2603.812 us; speedup vs baseline: 8.6550x; 8.6550x over previous
//
#include <hip/hip_runtime.h>
#include <math.h>

#define T_SEQ 120
#define BATCH 256
#define HID   512
#define G3    1536            // 3*HID
#define MROWS (BATCH*T_SEQ)   // 30720
#define TS    (T_SEQ*HID)     // 61440, row stride per batch in out buffers
#define KGATE 122880          // T_SEQ*2*HID

typedef __attribute__((ext_vector_type(8))) short bf16x8;
typedef __attribute__((ext_vector_type(4))) float f32x4;

__device__ __forceinline__ unsigned short f2bf(float f) {
    union { float f; unsigned u; } x; x.f = f;
    unsigned r = x.u + 0x7fffu + ((x.u >> 16) & 1u);   // RNE
    return (unsigned short)(r >> 16);
}
__device__ __forceinline__ float sigm_fast(float x) {
    return 1.f / (1.f + __expf(-x));
}
__device__ __forceinline__ float tanh_fast(float x) {
    float e = __expf(2.f * x);
    return 1.f - 2.f / (e + 1.f);
}

// ---------------------------------------------------------------------------
// build x_in[m=b*120+t][d] = concat(X_lag, X_cov)[t,b,d]
// ---------------------------------------------------------------------------
__global__ void build_x(const float* __restrict__ X_lag,
                        const float* __restrict__ X_cov,
                        float* __restrict__ x_in)
{
    int idx = blockIdx.x * 256 + threadIdx.x;      // < 30720*64
    int d = idx & 63;
    int m = idx >> 6;                               // b*120 + t
    int b = m / 120, t = m - b * 120;
    float v;
    if (d < 32) v = X_lag[((size_t)t * BATCH + b) * 32 + d];
    else        v = X_cov[((size_t)t * BATCH + b) * 32 + (d - 32)];
    x_in[idx] = v;
}

__global__ void cast_whh0(const float* __restrict__ W, unsigned short* __restrict__ o)
{
    int i = blockIdx.x * 256 + threadIdx.x;        // < 786432
    o[i] = f2bf(W[i]);
}

// Wcat1 [1536][1024]: cols 0..511 = W_hh1, cols 512..1023 = W_ih1
__global__ void cast_wcat1(const float* __restrict__ Whh, const float* __restrict__ Wih,
                           unsigned short* __restrict__ o)
{
    int i = blockIdx.x * 256 + threadIdx.x;        // < 1572864
    int row = i >> 10, c = i & 1023;
    float v = (c < 512) ? Whh[row * 512 + c] : Wih[row * 512 + (c - 512)];
    o[i] = f2bf(v);
}

__global__ void mkbias(const float* __restrict__ bih0, const float* __restrict__ bhh0,
                       const float* __restrict__ bih1, const float* __restrict__ bhh1,
                       float* __restrict__ bcomb0, float* __restrict__ bc1)
{
    int n = blockIdx.x * 256 + threadIdx.x;        // < 1536
    bcomb0[n] = bih0[n] + (n < 1024 ? bhh0[n] : 0.f);
    bc1[n]    = bih1[n] + (n < 1024 ? bhh1[n] : 0.f);
}

// ---------------------------------------------------------------------------
// Tiled f32 GEMM with TRANSPOSED write for gx0:
// C[(t*256+b)*1536 + n] = bias[n] + sum_k A[m=b*120+t][k]*B[n][k]
// ---------------------------------------------------------------------------
__global__ __launch_bounds__(256) void gemm_abt_t(
    const float* __restrict__ A, const float* __restrict__ B,
    const float* __restrict__ bias, float* __restrict__ C,
    int M, int N, int K)
{
    __shared__ float As[32][129];
    __shared__ float Bs[32][129];
    int m0 = blockIdx.x * 128;
    int n0 = blockIdx.y * 128;
    int tid = threadIdx.x;
    int tx = tid & 15, ty = tid >> 4;
    float acc[8][8] = {};
    for (int k0 = 0; k0 < K; k0 += 32) {
        #pragma unroll
        for (int i = 0; i < 16; i++) {
            int e = tid + i * 256;
            int row = e >> 5, col = e & 31;
            As[col][row] = A[(size_t)(m0 + row) * K + k0 + col];
            Bs[col][row] = B[(size_t)(n0 + row) * K + k0 + col];
        }
        __syncthreads();
        #pragma unroll
        for (int kk = 0; kk < 32; kk++) {
            float a[8], b[8];
            #pragma unroll
            for (int i = 0; i < 8; i++) a[i] = As[kk][ty + i * 16];
            #pragma unroll
            for (int j = 0; j < 8; j++) b[j] = Bs[kk][tx + j * 16];
            #pragma unroll
            for (int i = 0; i < 8; i++)
                #pragma unroll
                for (int j = 0; j < 8; j++) acc[i][j] += a[i] * b[j];
        }
        __syncthreads();
    }
    #pragma unroll
    for (int i = 0; i < 8; i++) {
        int m = m0 + ty + i * 16;
        int b = m / 120, t = m - b * 120;
        #pragma unroll
        for (int j = 0; j < 8; j++) {
            int n = n0 + tx + j * 16;
            C[((size_t)t * 256 + b) * G3 + n] = acc[i][j] + bias[n];
        }
    }
}

// ---------------------------------------------------------------------------
// Per-step GRU, fine-grained: 256 blocks x 256 threads (4 waves).
// Launch t: blocks [0,128) run layer0 step t; blocks [128,256) run layer1
// step t-1 (fuses the Wih1 input GEMM via K-concat [h1|h0] @ [Whh1;Wih1]^T).
// Block: jt = idx>>2 (32 j-tiles of 16 cols), bq = idx&3; wave w owns the
// 16-batch tile b0 = (bq*4+w)*16. Each weight byte is read by exactly ONE
// block per step (no duplication); per-XCD L2 keeps its weight slice hot
// across the 121 identical launches.
// ---------------------------------------------------------------------------
__global__ __launch_bounds__(256) void gru_step2(
    const float* __restrict__ gx0t,                  // [120][256][1536]
    const unsigned short* __restrict__ Whh0,         // [1536][512] bf16
    const unsigned short* __restrict__ Wcat1,        // [1536][1024] bf16
    const float* __restrict__ bhh0,
    const float* __restrict__ bhh1,
    const float* __restrict__ bc1,
    unsigned short* __restrict__ h0bf,               // [2][256][512]
    unsigned short* __restrict__ h1bf,               // [2][256][512]
    float* __restrict__ out0, float* __restrict__ out1,
    int t)
{
    const int blk   = blockIdx.x;
    const int layer = blk >> 7;
    const int idx   = blk & 127;
    const int jt    = idx >> 2, bq = idx & 3;
    const int w     = threadIdx.x >> 6, lane = threadIdx.x & 63;
    const int l15   = lane & 15, l4 = lane >> 4;
    const int j     = jt * 16 + l15;
    const int b0    = (bq * 4 + w) * 16;

    if (!layer) {
        if (t >= T_SEQ) return;
        f32x4 ar = {0,0,0,0}, az = {0,0,0,0}, anh = {0,0,0,0};
        if (t > 0) {
            const unsigned short* hp = h0bf + (size_t)((t & 1) ^ 1) * (256 * 512);
            #pragma unroll
            for (int ks = 0; ks < 16; ks++) {
                const int ko = ks * 32 + 8 * l4;
                bf16x8 A = *(const bf16x8*)(hp + (size_t)(b0 + l15) * 512 + ko);
                const unsigned short* wb = Whh0 + (size_t)j * 512 + ko;
                bf16x8 B0 = *(const bf16x8*)(wb);
                bf16x8 B1 = *(const bf16x8*)(wb + 512 * 512);
                bf16x8 B2 = *(const bf16x8*)(wb + 1024 * 512);
                ar  = __builtin_amdgcn_mfma_f32_16x16x32_bf16(A, B0, ar, 0, 0, 0);
                az  = __builtin_amdgcn_mfma_f32_16x16x32_bf16(A, B1, az, 0, 0, 0);
                anh = __builtin_amdgcn_mfma_f32_16x16x32_bf16(A, B2, anh, 0, 0, 0);
            }
        }
        const float bn = bhh0[1024 + j];
        unsigned short* hw = h0bf + (size_t)(t & 1) * (256 * 512);
        #pragma unroll
        for (int rr = 0; rr < 4; rr++) {
            int b = b0 + 4 * l4 + rr;
            const float* gp = gx0t + ((size_t)t * 256 + b) * G3 + j;
            float r = sigm_fast(gp[0] + ar[rr]);
            float z = sigm_fast(gp[512] + az[rr]);
            float n = tanh_fast(gp[1024] + r * (anh[rr] + bn));
            float hp_v = (t > 0) ? out0[(size_t)b * TS + (size_t)(t - 1) * 512 + j] : 0.f;
            float h = (1.f - z) * n + z * hp_v;
            out0[(size_t)b * TS + (size_t)t * 512 + j] = h;
            hw[(size_t)b * 512 + j] = f2bf(h);
        }
    } else {
        if (t == 0) return;
        const int tau = t - 1;
        f32x4 ar = {0,0,0,0}, az = {0,0,0,0}, anh = {0,0,0,0}, anx = {0,0,0,0};
        if (tau > 0) {
            const unsigned short* hp = h1bf + (size_t)((tau & 1) ^ 1) * (256 * 512);
            #pragma unroll
            for (int ks = 0; ks < 16; ks++) {
                const int ko = ks * 32 + 8 * l4;
                bf16x8 A = *(const bf16x8*)(hp + (size_t)(b0 + l15) * 512 + ko);
                const unsigned short* wb = Wcat1 + (size_t)j * 1024 + ko;
                bf16x8 B0 = *(const bf16x8*)(wb);
                bf16x8 B1 = *(const bf16x8*)(wb + 512 * 1024);
                bf16x8 B2 = *(const bf16x8*)(wb + 1024 * 1024);
                ar  = __builtin_amdgcn_mfma_f32_16x16x32_bf16(A, B0, ar, 0, 0, 0);
                az  = __builtin_amdgcn_mfma_f32_16x16x32_bf16(A, B1, az, 0, 0, 0);
                anh = __builtin_amdgcn_mfma_f32_16x16x32_bf16(A, B2, anh, 0, 0, 0);
            }
        }
        {
            const unsigned short* hx = h0bf + (size_t)(tau & 1) * (256 * 512);
            #pragma unroll
            for (int ks = 0; ks < 16; ks++) {
                const int ko = ks * 32 + 8 * l4;
                bf16x8 A = *(const bf16x8*)(hx + (size_t)(b0 + l15) * 512 + ko);
                const unsigned short* wb = Wcat1 + (size_t)j * 1024 + 512 + ko;
                bf16x8 B0 = *(const bf16x8*)(wb);
                bf16x8 B1 = *(const bf16x8*)(wb + 512 * 1024);
                bf16x8 B2 = *(const bf16x8*)(wb + 1024 * 1024);
                ar  = __builtin_amdgcn_mfma_f32_16x16x32_bf16(A, B0, ar, 0, 0, 0);
                az  = __builtin_amdgcn_mfma_f32_16x16x32_bf16(A, B1, az, 0, 0, 0);
                anx = __builtin_amdgcn_mfma_f32_16x16x32_bf16(A, B2, anx, 0, 0, 0);
            }
        }
        const float br = bc1[j], bz = bc1[512 + j];
        const float bnx = bc1[1024 + j], bn = bhh1[1024 + j];
        unsigned short* hw = h1bf + (size_t)(tau & 1) * (256 * 512);
        #pragma unroll
        for (int rr = 0; rr < 4; rr++) {
            int b = b0 + 4 * l4 + rr;
            float r = sigm_fast(ar[rr] + br);
            float z = sigm_fast(az[rr] + bz);
            float n = tanh_fast(anx[rr] + bnx + r * (anh[rr] + bn));
            float hp_v = (tau > 0) ? out1[(size_t)b * TS + (size_t)(tau - 1) * 512 + j] : 0.f;
            float h = (1.f - z) * n + z * hp_v;
            out1[(size_t)b * TS + (size_t)tau * 512 + j] = h;
            hw[(size_t)b * 512 + j] = f2bf(h);
        }
    }
}

// ---------------------------------------------------------------------------
// z partials: 960 blocks = (t, half, c-quarter of 128).   [verified round 4]
// ---------------------------------------------------------------------------
__global__ __launch_bounds__(256) void zpart_kernel(
    const float* __restrict__ out, const float* __restrict__ Gw,
    float* __restrict__ zp)
{
    __shared__ float Os[128][33];
    __shared__ float Gs[128][33];
    int bk = blockIdx.x;
    int t = bk >> 3, half = (bk >> 2) & 1, cq = bk & 3;
    int tid = threadIdx.x;
    int tx = tid & 15, ty = tid >> 4;
    float acc[8][8] = {};
    int cbase = cq * 128;
    for (int c0 = cbase; c0 < cbase + 128; c0 += 32) {
        #pragma unroll
        for (int i = 0; i < 16; i++) {
            int e = tid + i * 256;
            int row = e >> 5, col = e & 31;
            Os[row][col] = out[(size_t)(row + half * 128) * TS + (size_t)t * 512 + c0 + col];
            float v = 0.f;
            if (row < 120)
                v = Gw[(size_t)row * KGATE + (size_t)t * 1024 + half * 512 + c0 + col];
            Gs[row][col] = v;
        }
        __syncthreads();
        #pragma unroll
        for (int kk = 0; kk < 32; kk++) {
            float a[8], g[8];
            #pragma unroll
            for (int i = 0; i < 8; i++) a[i] = Os[ty + i * 16][kk];
            #pragma unroll
            for (int j = 0; j < 8; j++) g[j] = Gs[tx + j * 16][kk];
            #pragma unroll
            for (int i = 0; i < 8; i++)
                #pragma unroll
                for (int j = 0; j < 8; j++) acc[i][j] += a[i] * g[j];
        }
        __syncthreads();
    }
    float* zb = zp + (size_t)bk * (128 * 120);
    #pragma unroll
    for (int i = 0; i < 8; i++) {
        int ii = ty + i * 16;
        #pragma unroll
        for (int j = 0; j < 8; j++) {
            int r = tx + j * 16;
            if (r < 120) zb[ii * 120 + r] = acc[i][j];
        }
    }
}

__global__ void zreduce(const float* __restrict__ zp,
                        const float* __restrict__ gate_b_l,
                        float* __restrict__ z)
{
    int idx = blockIdx.x * 256 + threadIdx.x;
    if (idx >= 128 * 120) return;
    float s = 0.f;
    for (int c = 0; c < 960; c++) s += zp[(size_t)c * (128 * 120) + idx];
    z[idx] = s + gate_b_l[idx % 120];
}

__global__ __launch_bounds__(128) void bn_col(
    const float* __restrict__ z, const float* __restrict__ gamma,
    const float* __restrict__ beta, float* __restrict__ wm)
{
    int r = blockIdx.x, i = threadIdx.x;
    __shared__ float sh[2];
    float v = z[i * 120 + r];
    float s = v;
    for (int o = 32; o > 0; o >>= 1) s += __shfl_down(s, o);
    if ((i & 63) == 0) sh[i >> 6] = s;
    __syncthreads();
    float m = (sh[0] + sh[1]) * (1.f / 128.f);
    __syncthreads();
    float d = (v - m) * (v - m);
    for (int o = 32; o > 0; o >>= 1) d += __shfl_down(d, o);
    if ((i & 63) == 0) sh[i >> 6] = d;
    __syncthreads();
    float var = (sh[0] + sh[1]) * (1.f / 128.f);
    float w = 1.f / (1.f + expf(-(gamma[r] * (v - m) / sqrtf(var + 1e-5f) + beta[r])));
    __syncthreads();
    float ws_ = w;
    for (int o = 32; o > 0; o >>= 1) ws_ += __shfl_down(ws_, o);
    if ((i & 63) == 0) sh[i >> 6] = ws_;
    __syncthreads();
    if (i == 0) wm[r] = (sh[0] + sh[1]) * (1.f / 128.f);
}

__global__ __launch_bounds__(128) void softmax120(
    const float* __restrict__ wm, float* __restrict__ g_out,
    float* __restrict__ g_ws)
{
    int i = threadIdx.x;
    __shared__ float sh[2];
    float v = (i < 120) ? wm[i] : -1e30f;
    float m = v;
    for (int o = 32; o > 0; o >>= 1) m = fmaxf(m, __shfl_down(m, o));
    if ((i & 63) == 0) sh[i >> 6] = m;
    __syncthreads();
    float mx = fmaxf(sh[0], sh[1]);
    float e = (i < 120) ? expf(v - mx) : 0.f;
    __syncthreads();
    float se = e;
    for (int o = 32; o > 0; o >>= 1) se += __shfl_down(se, o);
    if ((i & 63) == 0) sh[i >> 6] = se;
    __syncthreads();
    float sum = sh[0] + sh[1];
    if (i < 120) { float g = e / sum; g_out[i] = g; g_ws[i] = g; }
}

__global__ void halfmeans(const float* __restrict__ out,
                          float* __restrict__ ms, float* __restrict__ mt)
{
    int idx = blockIdx.x * 256 + threadIdx.x;
    int half = idx >= TS;
    int tc = idx - half * TS;
    const float* base = out + (size_t)(half * 128) * TS + tc;
    float s = 0.f;
    for (int i = 0; i < 128; i++) s += base[(size_t)i * TS];
    s *= (1.f / 128.f);
    if (half) mt[tc] = s; else ms[tc] = s;
}

// coalesced: thread c accumulates over windowed j, block-reduce 512 lanes
__global__ __launch_bounds__(512) void transfer_part(
    const float* __restrict__ ms, const float* __restrict__ mt,
    const float* __restrict__ gw, const int* __restrict__ lenw,
    float* __restrict__ part)
{
    int t = blockIdx.x, c = threadIdx.x;
    int lw = lenw[0];
    int j0 = t - lw; if (j0 < 0) j0 = 0;
    int j1 = t + lw; if (j1 > 119) j1 = 119;
    float m_c = ms[(size_t)t * 512 + c];
    float acc = 0.f;
    for (int j = j0; j <= j1; j++) {
        float d = m_c - mt[(size_t)j * 512 + c];
        acc += d * d;
    }
    for (int o = 32; o > 0; o >>= 1) acc += __shfl_down(acc, o);
    __shared__ float sh[8];
    if ((c & 63) == 0) sh[c >> 6] = acc;
    __syncthreads();
    if (c == 0) {
        float s = 0.f;
        #pragma unroll
        for (int k = 0; k < 8; k++) s += sh[k];
        part[t] = gw[t] * s;
    }
}

// wave-per-row prediction head: grid = dsl*64 blocks, 4 waves each
__global__ __launch_bounds__(256) void yhat_kernel(
    const float* __restrict__ out1, const float* __restrict__ y,
    const float* __restrict__ fcW, const float* __restrict__ fcb,
    int dsl, float* __restrict__ dout, float* __restrict__ lp_rows)
{
    int wid = blockIdx.x * 4 + (threadIdx.x >> 6);   // 0..dsl*256-1
    int lane = threadIdx.x & 63;
    int tt = wid >> 8, b = wid & 255;
    int t = T_SEQ - dsl + tt;
    const float* row = out1 + (size_t)b * TS + (size_t)t * 512;
    float s = 0.f;
    #pragma unroll
    for (int k = 0; k < 8; k++) s += row[lane + 64 * k] * fcW[lane + 64 * k];
    for (int o = 32; o > 0; o >>= 1) s += __shfl_down(s, o);
    if (lane == 0) {
        float loc = s + fcb[0];
        float sp = fmaxf(loc, 0.f) + log1pf(expf(-fabsf(loc)));
        float scale = sp + 1e-6f;
        dout[2 + tt * 256 + b] = loc;
        dout[2 + dsl * 256 + tt * 256 + b] = scale;
        float yt = y[(size_t)t * 256 + b];
        float u = (yt - loc) / scale;
        lp_rows[wid] = -0.5f * u * u - logf(scale) - 0.91893853320467274f;
    }
}

__global__ __launch_bounds__(64) void finalize(
    const float* __restrict__ lp_rows, const float* __restrict__ part0,
    const float* __restrict__ part1, float* __restrict__ dout, int n_lp)
{
    int i = threadIdx.x;
    float s = 0.f;
    for (int k = i; k < n_lp; k += 64) s += lp_rows[k];
    for (int o = 32; o > 0; o >>= 1) s += __shfl_down(s, o);
    float tr = 0.f;
    for (int k = i; k < 120; k += 64) tr += part0[k] + part1[k];
    for (int o = 32; o > 0; o >>= 1) tr += __shfl_down(tr, o);
    if (i == 0) {
        float ly = -s / (float)n_lp;
        dout[1] = ly;
        dout[0] = ly + tr;
    }
}

// ---------------------------------------------------------------------------
extern "C" void kernel_launch(void* const* d_in, const int* in_sizes, int n_in,
                              void* d_out, int out_size, void* d_ws, size_t ws_size,
                              hipStream_t stream)
{
    const float* X_cov  = (const float*)d_in[1];
    const float* X_lag  = (const float*)d_in[2];
    const float* y      = (const float*)d_in[3];
    const int*   lenw   = (const int*)d_in[5];
    const float* W_ih0  = (const float*)d_in[6];
    const float* W_hh0  = (const float*)d_in[7];
    const float* b_ih0  = (const float*)d_in[8];
    const float* b_hh0  = (const float*)d_in[9];
    const float* W_ih1  = (const float*)d_in[10];
    const float* W_hh1  = (const float*)d_in[11];
    const float* b_ih1  = (const float*)d_in[12];
    const float* b_hh1  = (const float*)d_in[13];
    const float* gate_W = (const float*)d_in[14];
    const float* gate_b = (const float*)d_in[15];
    const float* bn_g   = (const float*)d_in[16];
    const float* bn_b   = (const float*)d_in[17];
    const float* fc_W   = (const float*)d_in[18];
    const float* fc_b   = (const float*)d_in[19];
    float* dout = (float*)d_out;
    float* ws   = (float*)d_ws;

    // workspace layout (float offsets). Aliases are time-disjoint:
    //  - zp aliases gx0t (gx0t dead after the last gru_step2)
    //  - lp_rows aliases x_in (dead after gemm_abt_t)
    float* x_in    = ws;                         // 1,966,080
    float* gx0t    = ws + 1966080;               // 47,185,920  [120][256][1536]
    float* out0    = ws + 49152000;              // 15,728,640
    float* out1    = ws + 64880640;              // 15,728,640
    unsigned short* Whh0bf  = (unsigned short*)(ws + 80609280);  // 786,432 ush
    unsigned short* Wcat1bf = (unsigned short*)(ws + 81002496);  // 1,572,864 ush
    unsigned short* h0bf    = (unsigned short*)(ws + 81788928);  // 262,144 ush
    unsigned short* h1bf    = (unsigned short*)(ws + 81920000);  // 262,144 ush
    float* zmat    = ws + 84295680;              // 15,360
    float* wm      = ws + 84311040;              // 120
    float* gw_ws   = ws + 84311160;              // 240
    float* msb     = ws + 84311400;              // 61,440
    float* mtb     = ws + 84372840;              // 61,440
    float* part    = ws + 84434280;              // 240
    float* bcomb0  = ws + 84434560;              // 1536
    float* bc1     = ws + 84436096;              // 1536
    float* zp      = gx0t;                       // 14,745,600 (alias)
    float* lp_rows = x_in;                       // dsl*256 (alias)

    int dsl = (out_size - 2 - 2 * T_SEQ) / (2 * BATCH);   // = 24

    build_x<<<dim3(7680), 256, 0, stream>>>(X_lag, X_cov, x_in);
    cast_whh0<<<dim3(3072), 256, 0, stream>>>(W_hh0, Whh0bf);
    cast_wcat1<<<dim3(6144), 256, 0, stream>>>(W_hh1, W_ih1, Wcat1bf);
    mkbias<<<dim3(6), 256, 0, stream>>>(b_ih0, b_hh0, b_ih1, b_hh1, bcomb0, bc1);

    gemm_abt_t<<<dim3(240, 12), 256, 0, stream>>>(x_in, W_ih0, bcomb0, gx0t,
                                                  MROWS, G3, 64);

    for (int t = 0; t <= T_SEQ; t++)
        gru_step2<<<dim3(256), 256, 0, stream>>>(gx0t, Whh0bf, Wcat1bf,
                                                 b_hh0, b_hh1, bc1,
                                                 h0bf, h1bf, out0, out1, t);

    for (int l = 0; l < 2; l++) {
        const float* o = l ? out1 : out0;
        zpart_kernel<<<960, 256, 0, stream>>>(o, gate_W + (size_t)l * 120 * KGATE, zp);
        zreduce<<<60, 256, 0, stream>>>(zp, gate_b + l * 120, zmat);
        bn_col<<<120, 128, 0, stream>>>(zmat, bn_g + l * 120, bn_b + l * 120, wm);
        softmax120<<<1, 128, 0, stream>>>(wm, dout + 2 + 2 * dsl * 256 + l * 120,
                                          gw_ws + l * 120);
        halfmeans<<<480, 256, 0, stream>>>(o, msb, mtb);
        transfer_part<<<120, 512, 0, stream>>>(msb, mtb, gw_ws + l * 120, lenw,
                                               part + l * 120);
    }

    yhat_kernel<<<dsl * 64, 256, 0, stream>>>(out1, y, fc_W, fc_b, dsl, dout, lp_rows);
    finalize<<<1, 64, 0, stream>>>(lp_rows, part, part + 120, dout, dsl * 256);
}